// Round 1
// baseline (1991.147 us; speedup 1.0000x reference)
//
#include <hip/hip_runtime.h>

#define N_NODES 50000
#define N_EDGES 800000
#define BLK 64

__global__ __launch_bounds__(256) void count_kernel(const int* __restrict__ ei,
                                                    float* __restrict__ cnt) {
    int e = blockIdx.x * 256 + threadIdx.x;
    if (e < N_EDGES) atomicAdd(&cnt[ei[N_EDGES + e]], 1.0f);
}

__global__ __launch_bounds__(256) void scatter_kernel(const int* __restrict__ ei,
                                                      const float* __restrict__ src_buf,
                                                      float* __restrict__ dst_buf) {
    int i = blockIdx.x * 256 + threadIdx.x;   // up to 51.2M < 2^31
    int e = i >> 6;
    int f = i & 63;
    if (e < N_EDGES) {
        int s = ei[e];
        int d = ei[N_EDGES + e];
        atomicAdd(&dst_buf[d * 64 + f], src_buf[s * 64 + f]);
    }
}

__global__ __launch_bounds__(256) void divide_kernel(float* __restrict__ buf,
                                                     const float* __restrict__ cnt) {
    int i = blockIdx.x * 256 + threadIdx.x;
    if (i < N_NODES * 64) {
        float c = cnt[i >> 6];
        buf[i] = buf[i] / fmaxf(c, 1.0f);
    }
}

__device__ __forceinline__ float sigm_(float v) { return 1.0f / (1.0f + __expf(-v)); }

__device__ __forceinline__ float tanh_(float v) {
    float e2 = __expf(-2.0f * fabsf(v));
    float r = (1.0f - e2) / (1.0f + e2);
    return copysignf(r, v);
}

// One GRU cell for one node per thread.
// X: input regs (static-indexed), Hreg: state regs (static-indexed, h_old),
// Hcol: this thread's LDS column (stride BLK floats), holds h_old on entry,
// h_new on exit (updated in place, index j touched exactly once).
__device__ __forceinline__ void gru_cell(const float (&X)[64], const float (&Hreg)[64],
                                         float* __restrict__ Hcol,
                                         const float* __restrict__ Wih,
                                         const float* __restrict__ Whh,
                                         const float* __restrict__ bih,
                                         const float* __restrict__ bhh) {
#pragma unroll 1
    for (int j = 0; j < 64; ++j) {
        float air = bih[j], aiz = bih[64 + j], ain = bih[128 + j];
        float ahr = bhh[j], ahz = bhh[64 + j], ahn = bhh[128 + j];
        const float* wr = Wih + j * 64;
        const float* wz = Wih + (64 + j) * 64;
        const float* wn = Wih + (128 + j) * 64;
        const float* ur = Whh + j * 64;
        const float* uz = Whh + (64 + j) * 64;
        const float* un = Whh + (128 + j) * 64;
#pragma unroll
        for (int k = 0; k < 64; ++k) {
            air = fmaf(X[k], wr[k], air);
            aiz = fmaf(X[k], wz[k], aiz);
            ain = fmaf(X[k], wn[k], ain);
            ahr = fmaf(Hreg[k], ur[k], ahr);
            ahz = fmaf(Hreg[k], uz[k], ahz);
            ahn = fmaf(Hreg[k], un[k], ahn);
        }
        float r = sigm_(air + ahr);
        float z = sigm_(aiz + ahz);
        float n = tanh_(fmaf(r, ahn, ain));
        float hold = Hcol[j * BLK];               // == h_old[j]
        Hcol[j * BLK] = (1.0f - z) * n + z * hold; // h_new[j]
    }
}

__global__ __launch_bounds__(BLK) void gru_kernel(
    const float* __restrict__ x0, const float* __restrict__ x1,
    const float* __restrict__ x2, const float* __restrict__ x3,
    const float* __restrict__ Wih0, const float* __restrict__ Whh0,
    const float* __restrict__ bih0, const float* __restrict__ bhh0,
    const float* __restrict__ Wih1, const float* __restrict__ Whh1,
    const float* __restrict__ bih1, const float* __restrict__ bhh1,
    const float* __restrict__ Wout, const float* __restrict__ bout,
    float* __restrict__ out) {
    __shared__ float H0[64][BLK];
    __shared__ float H1[64][BLK];
    const int tid = threadIdx.x;
    const int node = blockIdx.x * BLK + tid;
    const bool active = node < N_NODES;
    const int nc = active ? node : (N_NODES - 1);

    float A[64];  // input regs
    float B[64];  // state regs

#pragma unroll
    for (int k = 0; k < 64; ++k) {
        H0[k][tid] = 0.0f;
        H1[k][tid] = 0.0f;
    }

#pragma unroll 1
    for (int t = 0; t < 4; ++t) {
        const float* xp = (t == 0) ? x0 : (t == 1) ? x1 : (t == 2) ? x2 : x3;
        const float4* xrow = reinterpret_cast<const float4*>(xp + (size_t)nc * 64);
#pragma unroll
        for (int kc = 0; kc < 16; ++kc) {
            float4 v = xrow[kc];
            A[4 * kc + 0] = v.x;
            A[4 * kc + 1] = v.y;
            A[4 * kc + 2] = v.z;
            A[4 * kc + 3] = v.w;
        }
#pragma unroll
        for (int k = 0; k < 64; ++k) B[k] = H0[k][tid];   // h0_old
        gru_cell(A, B, &H0[0][tid], Wih0, Whh0, bih0, bhh0);
#pragma unroll
        for (int k = 0; k < 64; ++k) {
            A[k] = H0[k][tid];   // h0_new = layer-1 input
            B[k] = H1[k][tid];   // h1_old
        }
        gru_cell(A, B, &H1[0][tid], Wih1, Whh1, bih1, bhh1);
    }

    float acc = bout[0];
#pragma unroll
    for (int k = 0; k < 64; ++k) acc = fmaf(tanh_(H1[k][tid]), Wout[k], acc);
    if (active) out[node] = acc;
}

extern "C" void kernel_launch(void* const* d_in, const int* in_sizes, int n_in,
                              void* d_out, int out_size, void* d_ws, size_t ws_size,
                              hipStream_t stream) {
    const float* z    = (const float*)d_in[0];
    const int*   ei   = (const int*)d_in[1];
    const float* Wih0 = (const float*)d_in[2];
    const float* Whh0 = (const float*)d_in[3];
    const float* bih0 = (const float*)d_in[4];
    const float* bhh0 = (const float*)d_in[5];
    const float* Wih1 = (const float*)d_in[6];
    const float* Whh1 = (const float*)d_in[7];
    const float* bih1 = (const float*)d_in[8];
    const float* bhh1 = (const float*)d_in[9];
    const float* Wout = (const float*)d_in[10];
    const float* bout = (const float*)d_in[11];
    float* out = (float*)d_out;
    float* ws  = (float*)d_ws;

    float* cnt = ws;                 // 50000 floats (padded region 65536)
    float* x1  = ws + 65536;         // 3.2M floats
    float* x2  = x1 + 3200000;
    float* x3  = x2 + 3200000;

    hipMemsetAsync(cnt, 0, 50000 * sizeof(float), stream);
    hipMemsetAsync(x1, 0, 3 * 3200000 * sizeof(float), stream);

    count_kernel<<<(N_EDGES + 255) / 256, 256, 0, stream>>>(ei, cnt);

    scatter_kernel<<<(N_EDGES * 64) / 256, 256, 0, stream>>>(ei, z, x1);
    divide_kernel<<<(N_NODES * 64 + 255) / 256, 256, 0, stream>>>(x1, cnt);
    scatter_kernel<<<(N_EDGES * 64) / 256, 256, 0, stream>>>(ei, x1, x2);
    divide_kernel<<<(N_NODES * 64 + 255) / 256, 256, 0, stream>>>(x2, cnt);
    scatter_kernel<<<(N_EDGES * 64) / 256, 256, 0, stream>>>(ei, x2, x3);
    divide_kernel<<<(N_NODES * 64 + 255) / 256, 256, 0, stream>>>(x3, cnt);

    gru_kernel<<<(N_NODES + BLK - 1) / BLK, BLK, 0, stream>>>(
        z, x1, x2, x3, Wih0, Whh0, bih0, bhh0, Wih1, Whh1, bih1, bhh1,
        Wout, bout, out);
}

// Round 2
// 868.771 us; speedup vs baseline: 2.2919x; 2.2919x over previous
//
#include <hip/hip_runtime.h>

#define N_NODES 50000
#define N_EDGES 800000

typedef __attribute__((ext_vector_type(8))) short short8;
typedef __attribute__((ext_vector_type(4))) float f32x4;

__device__ __forceinline__ unsigned short f2bf_hi(float f) {
    unsigned u = __float_as_uint(f);
    unsigned r = u + 0x7fffu + ((u >> 16) & 1u);
    return (unsigned short)(r >> 16);
}
__device__ __forceinline__ float bf2f(unsigned short h) {
    return __uint_as_float(((unsigned)h) << 16);
}

__device__ __forceinline__ float sigm_(float v) { return 1.0f / (1.0f + __expf(-v)); }

__device__ __forceinline__ float tanh_(float v) {
    float e2 = __expf(-2.0f * fabsf(v));
    float r = (1.0f - e2) / (1.0f + e2);
    return copysignf(r, v);
}

// ---------------- aggregation (unchanged this round) ----------------

__global__ __launch_bounds__(256) void count_kernel(const int* __restrict__ ei,
                                                    float* __restrict__ cnt) {
    int e = blockIdx.x * 256 + threadIdx.x;
    if (e < N_EDGES) atomicAdd(&cnt[ei[N_EDGES + e]], 1.0f);
}

__global__ __launch_bounds__(256) void scatter_kernel(const int* __restrict__ ei,
                                                      const float* __restrict__ src_buf,
                                                      float* __restrict__ dst_buf) {
    int i = blockIdx.x * 256 + threadIdx.x;
    int e = i >> 6;
    int f = i & 63;
    if (e < N_EDGES) {
        int s = ei[e];
        int d = ei[N_EDGES + e];
        atomicAdd(&dst_buf[d * 64 + f], src_buf[s * 64 + f]);
    }
}

__global__ __launch_bounds__(256) void divide_kernel(float* __restrict__ buf,
                                                     const float* __restrict__ cnt) {
    int i = blockIdx.x * 256 + threadIdx.x;
    if (i < N_NODES * 64) {
        float c = cnt[i >> 6];
        buf[i] = buf[i] / fmaxf(c, 1.0f);
    }
}

// ---------------- weight prep: split fp32 W into bf16 hi/lo MFMA B-fragments ----
// Layout (ushort elems): [layer][mat][ct(12)][ks(2)][term(2)][lane(64)][e(8)]
// B-frag for 16x16x32: lane l supplies B[k = ks*32 + 8*(l>>4) + e][col = ct*16 + (l&15)]
// where B[k][col] = W[col_global][k].

__global__ __launch_bounds__(256) void wprep_kernel(
    const float* __restrict__ Wih0, const float* __restrict__ Whh0,
    const float* __restrict__ Wih1, const float* __restrict__ Whh1,
    unsigned short* __restrict__ wout) {
    int idx = blockIdx.x * 256 + threadIdx.x;   // 49152 threads
    if (idx >= 49152) return;
    int e = idx & 7;
    int lane = (idx >> 3) & 63;
    int ks = (idx >> 9) & 1;
    int r = idx >> 10;            // 0..47
    int ct = r % 12;
    int mat = (r / 12) & 1;
    int layer = r / 24;
    const float* W = layer ? (mat ? Whh1 : Wih1) : (mat ? Whh0 : Wih0);
    int j = ct * 16 + (lane & 15);
    int k = ks * 32 + ((lane >> 4) << 3) + e;
    float v = W[j * 64 + k];
    unsigned short hi = f2bf_hi(v);
    unsigned short lo = f2bf_hi(v - bf2f(hi));
    int base = layer * 49152 + mat * 24576 + ct * 2048 + ks * 1024;
    wout[base + lane * 8 + e] = hi;        // term 0
    wout[base + 512 + lane * 8 + e] = lo;  // term 1
}

// ---------------- fused 8-cell GRU stack, MFMA ----------------

__device__ __forceinline__ f32x4 mfma_bf16(short8 a, short8 b, f32x4 c) {
    return __builtin_amdgcn_mfma_f32_16x16x32_bf16(a, b, c, 0, 0, 0);
}

template <int LAYER>
__device__ __forceinline__ void gru_cell_mfma(
    int ct, int col16, int kgrp, int tid,
    const short8 (&wf)[2][2][2][2],
    float bias_a, float bias_b,
    const unsigned short (*Ahi)[72], const unsigned short (*Alo)[72],
    unsigned short (&Hhi)[2][32][72], unsigned short (&Hlo)[2][32][72],
    float (&G)[32][196], float (&Gn2)[32][68]) {
    f32x4 acc_a[2], acc_b[2];
#pragma unroll
    for (int rt = 0; rt < 2; ++rt) {
        acc_a[rt] = {bias_a, bias_a, bias_a, bias_a};
        acc_b[rt] = {bias_b, bias_b, bias_b, bias_b};
    }
#pragma unroll
    for (int rt = 0; rt < 2; ++rt) {
#pragma unroll
        for (int ks = 0; ks < 2; ++ks) {
            const int row = rt * 16 + col16;
            const int koff = ks * 32 + kgrp;
            short8 a_in_hi = *reinterpret_cast<const short8*>(&Ahi[row][koff]);
            short8 a_in_lo = *reinterpret_cast<const short8*>(&Alo[row][koff]);
            short8 a_h_hi = *reinterpret_cast<const short8*>(&Hhi[LAYER][row][koff]);
            short8 a_h_lo = *reinterpret_cast<const short8*>(&Hlo[LAYER][row][koff]);
            short8 bi0 = wf[LAYER][0][ks][0], bi1 = wf[LAYER][0][ks][1];
            short8 bh0 = wf[LAYER][1][ks][0], bh1 = wf[LAYER][1][ks][1];
            // input @ Wih^T  (3-term split)
            acc_a[rt] = mfma_bf16(a_in_hi, bi0, acc_a[rt]);
            acc_a[rt] = mfma_bf16(a_in_hi, bi1, acc_a[rt]);
            acc_a[rt] = mfma_bf16(a_in_lo, bi0, acc_a[rt]);
            // hidden @ Whh^T
            if (ct < 8) {   // r,z gates: accumulate into same pre-activation
                acc_a[rt] = mfma_bf16(a_h_hi, bh0, acc_a[rt]);
                acc_a[rt] = mfma_bf16(a_h_hi, bh1, acc_a[rt]);
                acc_a[rt] = mfma_bf16(a_h_lo, bh0, acc_a[rt]);
            } else {        // n gate: keep h-part separate
                acc_b[rt] = mfma_bf16(a_h_hi, bh0, acc_b[rt]);
                acc_b[rt] = mfma_bf16(a_h_hi, bh1, acc_b[rt]);
                acc_b[rt] = mfma_bf16(a_h_lo, bh0, acc_b[rt]);
            }
        }
    }
    // write pre-activations to LDS. C layout: col=lane&15, row=(lane>>4)*4+v
    const int q4 = (kgrp >> 3) * 4;
    const int gcol = ct * 16 + col16;
#pragma unroll
    for (int rt = 0; rt < 2; ++rt) {
#pragma unroll
        for (int v = 0; v < 4; ++v) {
            int grow = rt * 16 + q4 + v;
            G[grow][gcol] = acc_a[rt][v];
            if (ct >= 8) Gn2[grow][gcol - 128] = acc_b[rt][v];
        }
    }
    __syncthreads();
    // elementwise gates: 32 nodes x 64 features
    for (int i = tid; i < 2048; i += 768) {
        int m = i >> 6, j = i & 63;
        float rr = sigm_(G[m][j]);
        float zz = sigm_(G[m][64 + j]);
        float nn = tanh_(fmaf(rr, Gn2[m][j], G[m][128 + j]));
        float hold = bf2f(Hhi[LAYER][m][j]) + bf2f(Hlo[LAYER][m][j]);
        float hnew = fmaf(zz, hold - nn, nn);   // (1-z)n + z*h
        unsigned short hi = f2bf_hi(hnew);
        Hhi[LAYER][m][j] = hi;
        Hlo[LAYER][m][j] = f2bf_hi(hnew - bf2f(hi));
    }
    __syncthreads();
}

__global__ __launch_bounds__(768) void gru_kernel(
    const float* __restrict__ x0, const float* __restrict__ x1,
    const float* __restrict__ x2, const float* __restrict__ x3,
    const unsigned short* __restrict__ wprep,
    const float* __restrict__ bih0, const float* __restrict__ bhh0,
    const float* __restrict__ bih1, const float* __restrict__ bhh1,
    const float* __restrict__ Wout, const float* __restrict__ bout,
    float* __restrict__ out) {
    __shared__ float G[32][196];               // 25088 B
    __shared__ float Gn2[32][68];              //  8704 B
    __shared__ unsigned short Hhi[2][32][72];  //  9216 B
    __shared__ unsigned short Hlo[2][32][72];  //  9216 B
    __shared__ unsigned short Xhi[32][72];     //  4608 B
    __shared__ unsigned short Xlo[32][72];     //  4608 B  (total 61440 B)

    const int tid = threadIdx.x;
    const int lane = tid & 63;
    const int ct = tid >> 6;          // wave id 0..11 = col-tile
    const int col16 = lane & 15;
    const int kgrp = (lane >> 4) << 3;
    const int nodebase = blockIdx.x * 32;

    // load this wave's weight fragments (held in VGPRs for the whole kernel)
    short8 wf[2][2][2][2];
    {
        const short8* wp = reinterpret_cast<const short8*>(wprep);
#pragma unroll
        for (int layer = 0; layer < 2; ++layer)
#pragma unroll
            for (int mat = 0; mat < 2; ++mat)
#pragma unroll
                for (int ks = 0; ks < 2; ++ks)
#pragma unroll
                    for (int term = 0; term < 2; ++term)
                        wf[layer][mat][ks][term] =
                            wp[(layer * 49152 + mat * 24576 + ct * 2048 +
                                ks * 1024 + term * 512 + lane * 8) >> 3];
    }
    // per-lane gate biases
    const int gcol = ct * 16 + col16;
    float bias0_a, bias0_b, bias1_a, bias1_b;
    if (ct < 8) {
        bias0_a = bih0[gcol] + bhh0[gcol]; bias0_b = 0.0f;
        bias1_a = bih1[gcol] + bhh1[gcol]; bias1_b = 0.0f;
    } else {
        bias0_a = bih0[gcol]; bias0_b = bhh0[gcol];
        bias1_a = bih1[gcol]; bias1_b = bhh1[gcol];
    }

    // zero hidden states
    for (int i = tid; i < 2 * 32 * 72; i += 768) {
        (&Hhi[0][0][0])[i] = 0;
        (&Hlo[0][0][0])[i] = 0;
    }
    __syncthreads();

#pragma unroll 1
    for (int t = 0; t < 4; ++t) {
        const float* xp = (t == 0) ? x0 : (t == 1) ? x1 : (t == 2) ? x2 : x3;
        for (int i = tid; i < 2048; i += 768) {
            int m = i >> 6, k = i & 63;
            int node = nodebase + m;
            if (node >= N_NODES) node = N_NODES - 1;
            float v = xp[node * 64 + k];
            unsigned short hi = f2bf_hi(v);
            Xhi[m][k] = hi;
            Xlo[m][k] = f2bf_hi(v - bf2f(hi));
        }
        __syncthreads();
        gru_cell_mfma<0>(ct, col16, kgrp, tid, wf, bias0_a, bias0_b,
                         Xhi, Xlo, Hhi, Hlo, G, Gn2);
        gru_cell_mfma<1>(ct, col16, kgrp, tid, wf, bias1_a, bias1_b,
                         Hhi[0], Hlo[0], Hhi, Hlo, G, Gn2);
    }

    // output head: out = tanh(h1) . Wout + bout
    if (tid < 32) {
        int node = nodebase + tid;
        if (node < N_NODES) {
            float acc = bout[0];
#pragma unroll 1
            for (int j = 0; j < 64; ++j) {
                float h = bf2f(Hhi[1][tid][j]) + bf2f(Hlo[1][tid][j]);
                acc = fmaf(tanh_(h), Wout[j], acc);
            }
            out[node] = acc;
        }
    }
}

extern "C" void kernel_launch(void* const* d_in, const int* in_sizes, int n_in,
                              void* d_out, int out_size, void* d_ws, size_t ws_size,
                              hipStream_t stream) {
    const float* z    = (const float*)d_in[0];
    const int*   ei   = (const int*)d_in[1];
    const float* Wih0 = (const float*)d_in[2];
    const float* Whh0 = (const float*)d_in[3];
    const float* bih0 = (const float*)d_in[4];
    const float* bhh0 = (const float*)d_in[5];
    const float* Wih1 = (const float*)d_in[6];
    const float* Whh1 = (const float*)d_in[7];
    const float* bih1 = (const float*)d_in[8];
    const float* bhh1 = (const float*)d_in[9];
    const float* Wout = (const float*)d_in[10];
    const float* bout = (const float*)d_in[11];
    float* out = (float*)d_out;
    float* ws  = (float*)d_ws;

    float* cnt = ws;                  // 65536 floats
    float* x1  = ws + 65536;          // 3.2M floats each
    float* x2  = x1 + 3200000;
    float* x3  = x2 + 3200000;
    unsigned short* wprep = (unsigned short*)(ws + 9665536);  // 98304 ushorts

    hipMemsetAsync(cnt, 0, 50000 * sizeof(float), stream);
    hipMemsetAsync(x1, 0, 3 * 3200000 * sizeof(float), stream);

    wprep_kernel<<<192, 256, 0, stream>>>(Wih0, Whh0, Wih1, Whh1, wprep);
    count_kernel<<<(N_EDGES + 255) / 256, 256, 0, stream>>>(ei, cnt);

    scatter_kernel<<<(N_EDGES * 64) / 256, 256, 0, stream>>>(ei, z, x1);
    divide_kernel<<<(N_NODES * 64 + 255) / 256, 256, 0, stream>>>(x1, cnt);
    scatter_kernel<<<(N_EDGES * 64) / 256, 256, 0, stream>>>(ei, x1, x2);
    divide_kernel<<<(N_NODES * 64 + 255) / 256, 256, 0, stream>>>(x2, cnt);
    scatter_kernel<<<(N_EDGES * 64) / 256, 256, 0, stream>>>(ei, x2, x3);
    divide_kernel<<<(N_NODES * 64 + 255) / 256, 256, 0, stream>>>(x3, cnt);

    gru_kernel<<<(N_NODES + 31) / 32, 768, 0, stream>>>(
        z, x1, x2, x3, wprep, bih0, bhh0, bih1, bhh1, Wout, bout, out);
}

// Round 3
// 629.258 us; speedup vs baseline: 3.1643x; 1.3806x over previous
//
#include <hip/hip_runtime.h>

#define N_NODES 50000
#define N_EDGES 800000

typedef __attribute__((ext_vector_type(8))) short short8;
typedef __attribute__((ext_vector_type(4))) float f32x4;

__device__ __forceinline__ unsigned short f2bf_hi(float f) {
    unsigned u = __float_as_uint(f);
    unsigned r = u + 0x7fffu + ((u >> 16) & 1u);
    return (unsigned short)(r >> 16);
}
__device__ __forceinline__ float bf2f(unsigned short h) {
    return __uint_as_float(((unsigned)h) << 16);
}

__device__ __forceinline__ float sigm_(float v) { return 1.0f / (1.0f + __expf(-v)); }

__device__ __forceinline__ float tanh_(float v) {
    float e2 = __expf(-2.0f * fabsf(v));
    float r = (1.0f - e2) / (1.0f + e2);
    return copysignf(r, v);
}

// ---------------- CSR build ----------------

__global__ __launch_bounds__(256) void count_kernel(const int* __restrict__ ei,
                                                    int* __restrict__ deg) {
    int e = blockIdx.x * 256 + threadIdx.x;
    if (e < N_EDGES) atomicAdd(&deg[ei[N_EDGES + e]], 1);
}

__global__ __launch_bounds__(1024) void scan_kernel(const int* __restrict__ deg,
                                                    int* __restrict__ rowptr,
                                                    int* __restrict__ cur) {
    __shared__ int part[1024];
    const int tid = threadIdx.x;
    const int CH = 49;  // 1024*49 = 50176 >= 50000
    const int base = tid * CH;
    int s = 0;
#pragma unroll 1
    for (int i = 0; i < CH; ++i) {
        int idx = base + i;
        if (idx < N_NODES) s += deg[idx];
    }
    part[tid] = s;
    __syncthreads();
    for (int off = 1; off < 1024; off <<= 1) {
        int v = (tid >= off) ? part[tid - off] : 0;
        __syncthreads();
        part[tid] += v;
        __syncthreads();
    }
    int run = part[tid] - s;  // exclusive prefix of this thread's chunk
#pragma unroll 1
    for (int i = 0; i < CH; ++i) {
        int idx = base + i;
        if (idx < N_NODES) {
            rowptr[idx] = run;
            cur[idx] = run;
            run += deg[idx];
        }
    }
    if (tid == 1023) rowptr[N_NODES] = run;  // == N_EDGES
}

__global__ __launch_bounds__(256) void fill_kernel(const int* __restrict__ ei,
                                                   int* __restrict__ cur,
                                                   int* __restrict__ col) {
    int e = blockIdx.x * 256 + threadIdx.x;
    if (e < N_EDGES) {
        int s = ei[e];
        int d = ei[N_EDGES + e];
        int p = atomicAdd(&cur[d], 1);
        col[p] = s;
    }
}

// ---------------- gather-mean (one wave per node, lane = feature) ----------------

__global__ __launch_bounds__(256) void gather_kernel(const int* __restrict__ rowptr,
                                                     const int* __restrict__ col,
                                                     const float* __restrict__ src,
                                                     float* __restrict__ dst) {
    int gid = blockIdx.x * 256 + threadIdx.x;
    int node = gid >> 6;
    int lane = threadIdx.x & 63;
    if (node >= N_NODES) return;
    const int beg = rowptr[node], end = rowptr[node + 1];
    float a0 = 0.0f, a1 = 0.0f;
    int e = beg;
    for (; e + 1 < end; e += 2) {
        int c0 = col[e], c1 = col[e + 1];
        a0 += src[(size_t)c0 * 64 + lane];
        a1 += src[(size_t)c1 * 64 + lane];
    }
    if (e < end) a0 += src[(size_t)col[e] * 64 + lane];
    float inv = 1.0f / fmaxf((float)(end - beg), 1.0f);
    dst[(size_t)node * 64 + lane] = (a0 + a1) * inv;
}

// ---------------- weight prep: split fp32 W into bf16 hi/lo MFMA B-fragments ----

__global__ __launch_bounds__(256) void wprep_kernel(
    const float* __restrict__ Wih0, const float* __restrict__ Whh0,
    const float* __restrict__ Wih1, const float* __restrict__ Whh1,
    unsigned short* __restrict__ wout) {
    int idx = blockIdx.x * 256 + threadIdx.x;   // 49152 threads
    if (idx >= 49152) return;
    int e = idx & 7;
    int lane = (idx >> 3) & 63;
    int ks = (idx >> 9) & 1;
    int r = idx >> 10;            // 0..47
    int ct = r % 12;
    int mat = (r / 12) & 1;
    int layer = r / 24;
    const float* W = layer ? (mat ? Whh1 : Wih1) : (mat ? Whh0 : Wih0);
    int j = ct * 16 + (lane & 15);
    int k = ks * 32 + ((lane >> 4) << 3) + e;
    float v = W[j * 64 + k];
    unsigned short hi = f2bf_hi(v);
    unsigned short lo = f2bf_hi(v - bf2f(hi));
    int base = layer * 49152 + mat * 24576 + ct * 2048 + ks * 1024;
    wout[base + lane * 8 + e] = hi;        // term 0
    wout[base + 512 + lane * 8 + e] = lo;  // term 1
}

// ---------------- fused 8-cell GRU stack, MFMA ----------------

__device__ __forceinline__ f32x4 mfma_bf16(short8 a, short8 b, f32x4 c) {
    return __builtin_amdgcn_mfma_f32_16x16x32_bf16(a, b, c, 0, 0, 0);
}

template <int LAYER>
__device__ __forceinline__ void gru_cell_mfma(
    int ct, int col16, int kgrp, int tid,
    const short8 (&wf)[2][2][2][2],
    float bias_a, float bias_b,
    const unsigned short (*Ahi)[72], const unsigned short (*Alo)[72],
    unsigned short (&Hhi)[2][32][72], unsigned short (&Hlo)[2][32][72],
    float (&G)[32][196], float (&Gn2)[32][68]) {
    f32x4 acc_a[2], acc_b[2];
#pragma unroll
    for (int rt = 0; rt < 2; ++rt) {
        acc_a[rt] = {bias_a, bias_a, bias_a, bias_a};
        acc_b[rt] = {bias_b, bias_b, bias_b, bias_b};
    }
#pragma unroll
    for (int rt = 0; rt < 2; ++rt) {
#pragma unroll
        for (int ks = 0; ks < 2; ++ks) {
            const int row = rt * 16 + col16;
            const int koff = ks * 32 + kgrp;
            short8 a_in_hi = *reinterpret_cast<const short8*>(&Ahi[row][koff]);
            short8 a_in_lo = *reinterpret_cast<const short8*>(&Alo[row][koff]);
            short8 a_h_hi = *reinterpret_cast<const short8*>(&Hhi[LAYER][row][koff]);
            short8 a_h_lo = *reinterpret_cast<const short8*>(&Hlo[LAYER][row][koff]);
            short8 bi0 = wf[LAYER][0][ks][0], bi1 = wf[LAYER][0][ks][1];
            short8 bh0 = wf[LAYER][1][ks][0], bh1 = wf[LAYER][1][ks][1];
            // input @ Wih^T  (3-term split)
            acc_a[rt] = mfma_bf16(a_in_hi, bi0, acc_a[rt]);
            acc_a[rt] = mfma_bf16(a_in_hi, bi1, acc_a[rt]);
            acc_a[rt] = mfma_bf16(a_in_lo, bi0, acc_a[rt]);
            // hidden @ Whh^T
            if (ct < 8) {   // r,z gates: accumulate into same pre-activation
                acc_a[rt] = mfma_bf16(a_h_hi, bh0, acc_a[rt]);
                acc_a[rt] = mfma_bf16(a_h_hi, bh1, acc_a[rt]);
                acc_a[rt] = mfma_bf16(a_h_lo, bh0, acc_a[rt]);
            } else {        // n gate: keep h-part separate
                acc_b[rt] = mfma_bf16(a_h_hi, bh0, acc_b[rt]);
                acc_b[rt] = mfma_bf16(a_h_hi, bh1, acc_b[rt]);
                acc_b[rt] = mfma_bf16(a_h_lo, bh0, acc_b[rt]);
            }
        }
    }
    // write pre-activations to LDS. C layout: col=lane&15, row=(lane>>4)*4+v
    const int q4 = (kgrp >> 3) * 4;
    const int gcol = ct * 16 + col16;
#pragma unroll
    for (int rt = 0; rt < 2; ++rt) {
#pragma unroll
        for (int v = 0; v < 4; ++v) {
            int grow = rt * 16 + q4 + v;
            G[grow][gcol] = acc_a[rt][v];
            if (ct >= 8) Gn2[grow][gcol - 128] = acc_b[rt][v];
        }
    }
    __syncthreads();
    // elementwise gates: 32 nodes x 64 features
    for (int i = tid; i < 2048; i += 768) {
        int m = i >> 6, j = i & 63;
        float rr = sigm_(G[m][j]);
        float zz = sigm_(G[m][64 + j]);
        float nn = tanh_(fmaf(rr, Gn2[m][j], G[m][128 + j]));
        float hold = bf2f(Hhi[LAYER][m][j]) + bf2f(Hlo[LAYER][m][j]);
        float hnew = fmaf(zz, hold - nn, nn);   // (1-z)n + z*h
        unsigned short hi = f2bf_hi(hnew);
        Hhi[LAYER][m][j] = hi;
        Hlo[LAYER][m][j] = f2bf_hi(hnew - bf2f(hi));
    }
    __syncthreads();
}

__global__ __launch_bounds__(768) void gru_kernel(
    const float* __restrict__ x0, const float* __restrict__ x1,
    const float* __restrict__ x2, const float* __restrict__ x3,
    const unsigned short* __restrict__ wprep,
    const float* __restrict__ bih0, const float* __restrict__ bhh0,
    const float* __restrict__ bih1, const float* __restrict__ bhh1,
    const float* __restrict__ Wout, const float* __restrict__ bout,
    float* __restrict__ out) {
    __shared__ float G[32][196];               // 25088 B
    __shared__ float Gn2[32][68];              //  8704 B
    __shared__ unsigned short Hhi[2][32][72];  //  9216 B
    __shared__ unsigned short Hlo[2][32][72];  //  9216 B
    __shared__ unsigned short Xhi[32][72];     //  4608 B
    __shared__ unsigned short Xlo[32][72];     //  4608 B  (total 61440 B)

    const int tid = threadIdx.x;
    const int lane = tid & 63;
    const int ct = tid >> 6;          // wave id 0..11 = col-tile
    const int col16 = lane & 15;
    const int kgrp = (lane >> 4) << 3;
    const int nodebase = blockIdx.x * 32;

    // load this wave's weight fragments (held in VGPRs for the whole kernel)
    short8 wf[2][2][2][2];
    {
        const short8* wp = reinterpret_cast<const short8*>(wprep);
#pragma unroll
        for (int layer = 0; layer < 2; ++layer)
#pragma unroll
            for (int mat = 0; mat < 2; ++mat)
#pragma unroll
                for (int ks = 0; ks < 2; ++ks)
#pragma unroll
                    for (int term = 0; term < 2; ++term)
                        wf[layer][mat][ks][term] =
                            wp[(layer * 49152 + mat * 24576 + ct * 2048 +
                                ks * 1024 + term * 512 + lane * 8) >> 3];
    }
    // per-lane gate biases
    const int gcol = ct * 16 + col16;
    float bias0_a, bias0_b, bias1_a, bias1_b;
    if (ct < 8) {
        bias0_a = bih0[gcol] + bhh0[gcol]; bias0_b = 0.0f;
        bias1_a = bih1[gcol] + bhh1[gcol]; bias1_b = 0.0f;
    } else {
        bias0_a = bih0[gcol]; bias0_b = bhh0[gcol];
        bias1_a = bih1[gcol]; bias1_b = bhh1[gcol];
    }

    // zero hidden states
    for (int i = tid; i < 2 * 32 * 72; i += 768) {
        (&Hhi[0][0][0])[i] = 0;
        (&Hlo[0][0][0])[i] = 0;
    }
    __syncthreads();

#pragma unroll 1
    for (int t = 0; t < 4; ++t) {
        const float* xp = (t == 0) ? x0 : (t == 1) ? x1 : (t == 2) ? x2 : x3;
        for (int i = tid; i < 2048; i += 768) {
            int m = i >> 6, k = i & 63;
            int node = nodebase + m;
            if (node >= N_NODES) node = N_NODES - 1;
            float v = xp[node * 64 + k];
            unsigned short hi = f2bf_hi(v);
            Xhi[m][k] = hi;
            Xlo[m][k] = f2bf_hi(v - bf2f(hi));
        }
        __syncthreads();
        gru_cell_mfma<0>(ct, col16, kgrp, tid, wf, bias0_a, bias0_b,
                         Xhi, Xlo, Hhi, Hlo, G, Gn2);
        gru_cell_mfma<1>(ct, col16, kgrp, tid, wf, bias1_a, bias1_b,
                         Hhi[0], Hlo[0], Hhi, Hlo, G, Gn2);
    }

    // output head: out = tanh(h1) . Wout + bout
    if (tid < 32) {
        int node = nodebase + tid;
        if (node < N_NODES) {
            float acc = bout[0];
#pragma unroll 1
            for (int j = 0; j < 64; ++j) {
                float h = bf2f(Hhi[1][tid][j]) + bf2f(Hlo[1][tid][j]);
                acc = fmaf(tanh_(h), Wout[j], acc);
            }
            out[node] = acc;
        }
    }
}

extern "C" void kernel_launch(void* const* d_in, const int* in_sizes, int n_in,
                              void* d_out, int out_size, void* d_ws, size_t ws_size,
                              hipStream_t stream) {
    const float* z    = (const float*)d_in[0];
    const int*   ei   = (const int*)d_in[1];
    const float* Wih0 = (const float*)d_in[2];
    const float* Whh0 = (const float*)d_in[3];
    const float* bih0 = (const float*)d_in[4];
    const float* bhh0 = (const float*)d_in[5];
    const float* Wih1 = (const float*)d_in[6];
    const float* Whh1 = (const float*)d_in[7];
    const float* bih1 = (const float*)d_in[8];
    const float* bhh1 = (const float*)d_in[9];
    const float* Wout = (const float*)d_in[10];
    const float* bout = (const float*)d_in[11];
    float* out = (float*)d_out;
    float* ws  = (float*)d_ws;

    float* x1 = ws;                   // 3.2M floats each
    float* x2 = x1 + 3200000;
    float* x3 = x2 + 3200000;
    unsigned short* wprep = (unsigned short*)(x3 + 3200000);  // 98304 ushorts
    int* rowptr = (int*)(ws + 9600000 + 49152);  // 50001 ints
    int* deg    = rowptr + 50002;                // 50000 ints
    int* cur    = deg + 50000;                   // 50000 ints
    int* col    = cur + 50000;                   // 800000 ints

    hipMemsetAsync(deg, 0, 50000 * sizeof(int), stream);

    wprep_kernel<<<192, 256, 0, stream>>>(Wih0, Whh0, Wih1, Whh1, wprep);
    count_kernel<<<(N_EDGES + 255) / 256, 256, 0, stream>>>(ei, deg);
    scan_kernel<<<1, 1024, 0, stream>>>(deg, rowptr, cur);
    fill_kernel<<<(N_EDGES + 255) / 256, 256, 0, stream>>>(ei, cur, col);

    gather_kernel<<<(N_NODES * 64 + 255) / 256, 256, 0, stream>>>(rowptr, col, z, x1);
    gather_kernel<<<(N_NODES * 64 + 255) / 256, 256, 0, stream>>>(rowptr, col, x1, x2);
    gather_kernel<<<(N_NODES * 64 + 255) / 256, 256, 0, stream>>>(rowptr, col, x2, x3);

    gru_kernel<<<(N_NODES + 31) / 32, 768, 0, stream>>>(
        z, x1, x2, x3, wprep, bih0, bhh0, bih1, bhh1, Wout, bout, out);
}

// Round 4
// 385.348 us; speedup vs baseline: 5.1671x; 1.6330x over previous
//
#include <hip/hip_runtime.h>
#include <hip/hip_bf16.h>

#define N_NODES 50000
#define N_EDGES 800000

typedef __attribute__((ext_vector_type(8))) short short8;
typedef __attribute__((ext_vector_type(4))) float f32x4;

__device__ __forceinline__ unsigned short f2bf_hi(float f) {
    unsigned u = __float_as_uint(f);
    unsigned r = u + 0x7fffu + ((u >> 16) & 1u);
    return (unsigned short)(r >> 16);
}
__device__ __forceinline__ float bf2f(unsigned short h) {
    return __uint_as_float(((unsigned)h) << 16);
}
__device__ __forceinline__ float u2f(unsigned u) { return __uint_as_float(u); }

// packs bf16(a) into low16, bf16(b) into high16 (one v_cvt_pk_bf16_f32)
__device__ __forceinline__ unsigned pack_bf2(float a, float b) {
    float2 t{a, b};
    __hip_bfloat162 r = __float22bfloat162_rn(t);
    return *reinterpret_cast<unsigned*>(&r);
}

__device__ __forceinline__ float sigm_(float v) {
    return __builtin_amdgcn_rcpf(1.0f + __expf(-v));
}
__device__ __forceinline__ float tanh2_(float a) {  // tanh(a) = 2/(1+e^-2a) - 1
    float e = __expf(-2.0f * a);
    return fmaf(2.0f, __builtin_amdgcn_rcpf(1.0f + e), -1.0f);
}

// ---------------- CSR build ----------------

__global__ __launch_bounds__(256) void count_kernel(const int* __restrict__ ei,
                                                    int* __restrict__ deg) {
    int e = blockIdx.x * 256 + threadIdx.x;
    if (e < N_EDGES) atomicAdd(&deg[ei[N_EDGES + e]], 1);
}

// 49 blocks x 256 threads: per-1024-chunk partial sums (coalesced)
__global__ __launch_bounds__(256) void scan_part(const int* __restrict__ deg,
                                                 int* __restrict__ part) {
    __shared__ int sm[256];
    int b = blockIdx.x, t = threadIdx.x;
    int s = 0;
#pragma unroll
    for (int i = 0; i < 4; ++i) {
        int idx = b * 1024 + i * 256 + t;
        if (idx < N_NODES) s += deg[idx];
    }
    sm[t] = s;
    __syncthreads();
    for (int off = 128; off; off >>= 1) {
        if (t < off) sm[t] += sm[t + off];
        __syncthreads();
    }
    if (t == 0) part[b] = sm[0];
}

// 1 block x 64 threads: exclusive scan of 49 partials
__global__ __launch_bounds__(64) void scan_top(const int* __restrict__ part,
                                               int* __restrict__ pref) {
    int lane = threadIdx.x;
    int v = (lane < 49) ? part[lane] : 0;
    for (int off = 1; off < 64; off <<= 1) {
        int u = __shfl_up(v, off);
        if (lane >= off) v += u;
    }
    if (lane == 0) pref[0] = 0;
    if (lane < 49) pref[lane + 1] = v;
}

// 49 blocks x 1024 threads: intra-chunk scan + write rowptr/cur (coalesced)
__global__ __launch_bounds__(1024) void scan_final(const int* __restrict__ deg,
                                                   const int* __restrict__ pref,
                                                   int* __restrict__ rowptr,
                                                   int* __restrict__ cur) {
    __shared__ int sm[1024];
    int b = blockIdx.x, t = threadIdx.x;
    int idx = b * 1024 + t;
    int d = (idx < N_NODES) ? deg[idx] : 0;
    sm[t] = d;
    __syncthreads();
    for (int off = 1; off < 1024; off <<= 1) {
        int u = (t >= off) ? sm[t - off] : 0;
        __syncthreads();
        sm[t] += u;
        __syncthreads();
    }
    int excl = pref[b] + sm[t] - d;
    if (idx < N_NODES) {
        rowptr[idx] = excl;
        cur[idx] = excl;
    } else if (idx == N_NODES) {
        rowptr[idx] = excl;  // == N_EDGES
    }
}

__global__ __launch_bounds__(256) void fill_kernel(const int* __restrict__ ei,
                                                   int* __restrict__ cur,
                                                   int* __restrict__ col) {
    int e = blockIdx.x * 256 + threadIdx.x;
    if (e < N_EDGES) {
        int s = ei[e];
        int d = ei[N_EDGES + e];
        int p = atomicAdd(&cur[d], 1);
        col[p] = s;
    }
}

// ------- gather-mean: one wave per node; 4 x 16-lane groups, float4 rows -------

__global__ __launch_bounds__(256) void gather_kernel(const int* __restrict__ rowptr,
                                                     const int* __restrict__ col,
                                                     const float* __restrict__ src,
                                                     float* __restrict__ dst) {
    int node = (blockIdx.x * 256 + threadIdx.x) >> 6;
    if (node >= N_NODES) return;
    const int lane = threadIdx.x & 63;
    const int g = lane >> 4;     // edge sub-group 0..3
    const int l16 = lane & 15;   // float4 index within row
    const int beg = rowptr[node], end = rowptr[node + 1];
    const float4* s4 = reinterpret_cast<const float4*>(src);

    float4 a0 = {0.f, 0.f, 0.f, 0.f}, a1 = {0.f, 0.f, 0.f, 0.f};
#pragma unroll 1
    for (int e = beg + 2 * g; e < end; e += 8) {
        int c0 = col[e];
        float4 v0 = s4[c0 * 16 + l16];
        if (e + 1 < end) {
            int c1 = col[e + 1];
            float4 v1 = s4[c1 * 16 + l16];
            a1.x += v1.x; a1.y += v1.y; a1.z += v1.z; a1.w += v1.w;
        }
        a0.x += v0.x; a0.y += v0.y; a0.z += v0.z; a0.w += v0.w;
    }
    a0.x += a1.x; a0.y += a1.y; a0.z += a1.z; a0.w += a1.w;
    // reduce across the 4 groups (lanes ^16, ^32)
#pragma unroll
    for (int m = 16; m <= 32; m <<= 1) {
        a0.x += __shfl_xor(a0.x, m);
        a0.y += __shfl_xor(a0.y, m);
        a0.z += __shfl_xor(a0.z, m);
        a0.w += __shfl_xor(a0.w, m);
    }
    if (g == 0) {
        float inv = __builtin_amdgcn_rcpf(fmaxf((float)(end - beg), 1.0f));
        float4 r = {a0.x * inv, a0.y * inv, a0.z * inv, a0.w * inv};
        reinterpret_cast<float4*>(dst)[node * 16 + l16] = r;
    }
}

// ---------------- weight prep: split fp32 W into bf16 hi/lo MFMA B-fragments ----

__global__ __launch_bounds__(256) void wprep_kernel(
    const float* __restrict__ Wih0, const float* __restrict__ Whh0,
    const float* __restrict__ Wih1, const float* __restrict__ Whh1,
    unsigned short* __restrict__ wout) {
    int idx = blockIdx.x * 256 + threadIdx.x;   // 49152 threads
    if (idx >= 49152) return;
    int e = idx & 7;
    int lane = (idx >> 3) & 63;
    int ks = (idx >> 9) & 1;
    int r = idx >> 10;            // 0..47
    int ct = r % 12;
    int mat = (r / 12) & 1;
    int layer = r / 24;
    const float* W = layer ? (mat ? Whh1 : Wih1) : (mat ? Whh0 : Wih0);
    int j = ct * 16 + (lane & 15);
    int k = ks * 32 + ((lane >> 4) << 3) + e;
    float v = W[j * 64 + k];
    unsigned short hi = f2bf_hi(v);
    unsigned short lo = f2bf_hi(v - bf2f(hi));
    int base = layer * 49152 + mat * 24576 + ct * 2048 + ks * 1024;
    wout[base + lane * 8 + e] = hi;        // term 0
    wout[base + 512 + lane * 8 + e] = lo;  // term 1
}

// ---------------- fused 8-cell GRU stack, MFMA ----------------

__device__ __forceinline__ f32x4 mfma_bf16(short8 a, short8 b, f32x4 c) {
    return __builtin_amdgcn_mfma_f32_16x16x32_bf16(a, b, c, 0, 0, 0);
}

template <int LAYER>
__device__ __forceinline__ void gru_cell_mfma(
    int ct, int col16, int kgrp, int tid,
    const short8 (&wf)[2][2][2][2],
    float bias_a, float bias_b,
    const unsigned short (*Ahi)[72], const unsigned short (*Alo)[72],
    unsigned short (&Hhi)[2][32][72], unsigned short (&Hlo)[2][32][72],
    float (&G)[32][196], float (&Gn2)[32][68]) {
    f32x4 acc_a[2], acc_b[2];
#pragma unroll
    for (int rt = 0; rt < 2; ++rt) {
        acc_a[rt] = {bias_a, bias_a, bias_a, bias_a};
        acc_b[rt] = {bias_b, bias_b, bias_b, bias_b};
    }
#pragma unroll
    for (int rt = 0; rt < 2; ++rt) {
#pragma unroll
        for (int ks = 0; ks < 2; ++ks) {
            const int row = rt * 16 + col16;
            const int koff = ks * 32 + kgrp;
            short8 a_in_hi = *reinterpret_cast<const short8*>(&Ahi[row][koff]);
            short8 a_in_lo = *reinterpret_cast<const short8*>(&Alo[row][koff]);
            short8 a_h_hi = *reinterpret_cast<const short8*>(&Hhi[LAYER][row][koff]);
            short8 a_h_lo = *reinterpret_cast<const short8*>(&Hlo[LAYER][row][koff]);
            short8 bi0 = wf[LAYER][0][ks][0], bi1 = wf[LAYER][0][ks][1];
            short8 bh0 = wf[LAYER][1][ks][0], bh1 = wf[LAYER][1][ks][1];
            acc_a[rt] = mfma_bf16(a_in_hi, bi0, acc_a[rt]);
            acc_a[rt] = mfma_bf16(a_in_hi, bi1, acc_a[rt]);
            acc_a[rt] = mfma_bf16(a_in_lo, bi0, acc_a[rt]);
            if (ct < 8) {   // r,z gates: accumulate into same pre-activation
                acc_a[rt] = mfma_bf16(a_h_hi, bh0, acc_a[rt]);
                acc_a[rt] = mfma_bf16(a_h_hi, bh1, acc_a[rt]);
                acc_a[rt] = mfma_bf16(a_h_lo, bh0, acc_a[rt]);
            } else {        // n gate: keep h-part separate
                acc_b[rt] = mfma_bf16(a_h_hi, bh0, acc_b[rt]);
                acc_b[rt] = mfma_bf16(a_h_hi, bh1, acc_b[rt]);
                acc_b[rt] = mfma_bf16(a_h_lo, bh0, acc_b[rt]);
            }
        }
    }
    // write pre-activations to LDS. C layout: col=lane&15, row=(lane>>4)*4+v
    const int q4 = (kgrp >> 3) * 4;
    const int gcol = ct * 16 + col16;
#pragma unroll
    for (int rt = 0; rt < 2; ++rt) {
#pragma unroll
        for (int v = 0; v < 4; ++v) {
            int grow = rt * 16 + q4 + v;
            G[grow][gcol] = acc_a[rt][v];
            if (ct >= 8) Gn2[grow][gcol - 128] = acc_b[rt][v];
        }
    }
    __syncthreads();
    // elementwise gates: 1024 j-pairs over first 512 threads
    if (tid < 512) {
#pragma unroll
        for (int h2 = 0; h2 < 2; ++h2) {
            int p = tid + h2 * 512;
            int m = p >> 5, j0 = (p & 31) * 2;
            float gr0 = G[m][j0],       gr1 = G[m][j0 + 1];
            float gz0 = G[m][64 + j0],  gz1 = G[m][64 + j0 + 1];
            float gn0 = G[m][128 + j0], gn1 = G[m][128 + j0 + 1];
            float gm0 = Gn2[m][j0],     gm1 = Gn2[m][j0 + 1];
            unsigned hhi = *reinterpret_cast<const unsigned*>(&Hhi[LAYER][m][j0]);
            unsigned hlo = *reinterpret_cast<const unsigned*>(&Hlo[LAYER][m][j0]);
            float hold0 = u2f(hhi << 16) + u2f(hlo << 16);
            float hold1 = u2f(hhi & 0xffff0000u) + u2f(hlo & 0xffff0000u);
            float r0 = sigm_(gr0), r1 = sigm_(gr1);
            float z0 = sigm_(gz0), z1 = sigm_(gz1);
            float n0 = tanh2_(fmaf(r0, gm0, gn0));
            float n1 = tanh2_(fmaf(r1, gm1, gn1));
            float h0 = fmaf(z0, hold0 - n0, n0);
            float h1 = fmaf(z1, hold1 - n1, n1);
            unsigned phi = pack_bf2(h0, h1);
            float l0 = h0 - u2f(phi << 16);
            float l1 = h1 - u2f(phi & 0xffff0000u);
            unsigned plo = pack_bf2(l0, l1);
            *reinterpret_cast<unsigned*>(&Hhi[LAYER][m][j0]) = phi;
            *reinterpret_cast<unsigned*>(&Hlo[LAYER][m][j0]) = plo;
        }
    }
    __syncthreads();
}

__global__ __launch_bounds__(768) void gru_kernel(
    const float* __restrict__ x0, const float* __restrict__ x1,
    const float* __restrict__ x2, const float* __restrict__ x3,
    const unsigned short* __restrict__ wprep,
    const float* __restrict__ bih0, const float* __restrict__ bhh0,
    const float* __restrict__ bih1, const float* __restrict__ bhh1,
    const float* __restrict__ Wout, const float* __restrict__ bout,
    float* __restrict__ out) {
    __shared__ __align__(16) float G[32][196];               // 25088 B
    __shared__ __align__(16) float Gn2[32][68];              //  8704 B
    __shared__ __align__(16) unsigned short Hhi[2][32][72];  //  9216 B
    __shared__ __align__(16) unsigned short Hlo[2][32][72];  //  9216 B
    __shared__ __align__(16) unsigned short Xhi[32][72];     //  4608 B
    __shared__ __align__(16) unsigned short Xlo[32][72];     //  4608 B

    const int tid = threadIdx.x;
    const int lane = tid & 63;
    const int ct = tid >> 6;          // wave id 0..11 = col-tile
    const int col16 = lane & 15;
    const int kgrp = (lane >> 4) << 3;
    const int nodebase = blockIdx.x * 32;

    short8 wf[2][2][2][2];
    {
        const short8* wp = reinterpret_cast<const short8*>(wprep);
#pragma unroll
        for (int layer = 0; layer < 2; ++layer)
#pragma unroll
            for (int mat = 0; mat < 2; ++mat)
#pragma unroll
                for (int ks = 0; ks < 2; ++ks)
#pragma unroll
                    for (int term = 0; term < 2; ++term)
                        wf[layer][mat][ks][term] =
                            wp[(layer * 49152 + mat * 24576 + ct * 2048 +
                                ks * 1024 + term * 512 + lane * 8) >> 3];
    }
    const int gcol = ct * 16 + col16;
    float bias0_a, bias0_b, bias1_a, bias1_b;
    if (ct < 8) {
        bias0_a = bih0[gcol] + bhh0[gcol]; bias0_b = 0.0f;
        bias1_a = bih1[gcol] + bhh1[gcol]; bias1_b = 0.0f;
    } else {
        bias0_a = bih0[gcol]; bias0_b = bhh0[gcol];
        bias1_a = bih1[gcol]; bias1_b = bhh1[gcol];
    }

    for (int i = tid; i < 2304; i += 768) {
        reinterpret_cast<unsigned*>(&Hhi[0][0][0])[i] = 0;
        reinterpret_cast<unsigned*>(&Hlo[0][0][0])[i] = 0;
    }
    __syncthreads();

#pragma unroll 1
    for (int t = 0; t < 4; ++t) {
        const float* xp = (t == 0) ? x0 : (t == 1) ? x1 : (t == 2) ? x2 : x3;
        if (tid < 512) {
#pragma unroll
            for (int h2 = 0; h2 < 2; ++h2) {
                int p = tid + h2 * 512;
                int m = p >> 5, k0 = (p & 31) * 2;
                int node = nodebase + m;
                if (node >= N_NODES) node = N_NODES - 1;
                float2 v = *reinterpret_cast<const float2*>(xp + (size_t)node * 64 + k0);
                unsigned phi = pack_bf2(v.x, v.y);
                float l0 = v.x - u2f(phi << 16);
                float l1 = v.y - u2f(phi & 0xffff0000u);
                *reinterpret_cast<unsigned*>(&Xhi[m][k0]) = phi;
                *reinterpret_cast<unsigned*>(&Xlo[m][k0]) = pack_bf2(l0, l1);
            }
        }
        __syncthreads();
        gru_cell_mfma<0>(ct, col16, kgrp, tid, wf, bias0_a, bias0_b,
                         Xhi, Xlo, Hhi, Hlo, G, Gn2);
        gru_cell_mfma<1>(ct, col16, kgrp, tid, wf, bias1_a, bias1_b,
                         Hhi[0], Hlo[0], Hhi, Hlo, G, Gn2);
    }

    // output head: out[node] = tanh(h1[node]) . Wout + bout  (16 lanes per node)
    if (tid < 512) {
        int m = tid >> 4, l16 = tid & 15;
        float acc = 0.0f;
#pragma unroll
        for (int q = 0; q < 4; ++q) {
            int j = l16 * 4 + q;
            float h = bf2f(Hhi[1][m][j]) + bf2f(Hlo[1][m][j]);
            acc = fmaf(tanh2_(h), Wout[j], acc);
        }
        acc += __shfl_down(acc, 8, 16);
        acc += __shfl_down(acc, 4, 16);
        acc += __shfl_down(acc, 2, 16);
        acc += __shfl_down(acc, 1, 16);
        int node = nodebase + m;
        if (l16 == 0 && node < N_NODES) out[node] = acc + bout[0];
    }
}

extern "C" void kernel_launch(void* const* d_in, const int* in_sizes, int n_in,
                              void* d_out, int out_size, void* d_ws, size_t ws_size,
                              hipStream_t stream) {
    const float* z    = (const float*)d_in[0];
    const int*   ei   = (const int*)d_in[1];
    const float* Wih0 = (const float*)d_in[2];
    const float* Whh0 = (const float*)d_in[3];
    const float* bih0 = (const float*)d_in[4];
    const float* bhh0 = (const float*)d_in[5];
    const float* Wih1 = (const float*)d_in[6];
    const float* Whh1 = (const float*)d_in[7];
    const float* bih1 = (const float*)d_in[8];
    const float* bhh1 = (const float*)d_in[9];
    const float* Wout = (const float*)d_in[10];
    const float* bout = (const float*)d_in[11];
    float* out = (float*)d_out;
    float* ws  = (float*)d_ws;

    float* x1 = ws;                   // 3.2M floats each
    float* x2 = x1 + 3200000;
    float* x3 = x2 + 3200000;
    unsigned short* wprep = (unsigned short*)(x3 + 3200000);  // 98304 ushorts
    int* rowptr = (int*)(ws + 9600000 + 49152);  // 50001 ints (pad to 50004)
    int* deg    = rowptr + 50004;                // 50000 ints
    int* cur    = deg + 50000;                   // 50000 ints
    int* col    = cur + 50000;                   // 800000 ints
    int* part   = col + 800000;                  // 64 ints
    int* pref   = part + 64;                     // 64 ints

    hipMemsetAsync(deg, 0, 50000 * sizeof(int), stream);

    wprep_kernel<<<192, 256, 0, stream>>>(Wih0, Whh0, Wih1, Whh1, wprep);
    count_kernel<<<(N_EDGES + 255) / 256, 256, 0, stream>>>(ei, deg);
    scan_part<<<49, 256, 0, stream>>>(deg, part);
    scan_top<<<1, 64, 0, stream>>>(part, pref);
    scan_final<<<49, 1024, 0, stream>>>(deg, pref, rowptr, cur);
    fill_kernel<<<(N_EDGES + 255) / 256, 256, 0, stream>>>(ei, cur, col);

    gather_kernel<<<(N_NODES * 64 + 255) / 256, 256, 0, stream>>>(rowptr, col, z, x1);
    gather_kernel<<<(N_NODES * 64 + 255) / 256, 256, 0, stream>>>(rowptr, col, x1, x2);
    gather_kernel<<<(N_NODES * 64 + 255) / 256, 256, 0, stream>>>(rowptr, col, x2, x3);

    gru_kernel<<<(N_NODES + 31) / 32, 768, 0, stream>>>(
        z, x1, x2, x3, wprep, bih0, bhh0, bih1, bhh1, Wout, bout, out);
}